// Round 2
// baseline (114.812 us; speedup 1.0000x reference)
//
#include <hip/hip_runtime.h>
#include <math.h>

// Problem constants (match reference)
#define T_ 16
#define C_ 4
#define S_ 256
static constexpr float DT      = 0.05f;
static constexpr float JITTER  = 1e-5f;
static constexpr float CLIPV   = 1e4f;

// Output layout (floats, concatenated in return order)
static constexpr int TR_SIZE     = T_ * (C_ * S_) * (C_ * S_);   // 16,777,216
static constexpr int DRIFT_OFF   = TR_SIZE;                       // [T,C,C,2] = 512
static constexpr int DISP_OFF    = DRIFT_OFF + T_ * C_ * C_ * 2;  // [T,C,C,2,2] = 1024
static constexpr int SCALES_OFF  = DISP_OFF + T_ * C_ * C_ * 4;   // [C,C] = 16
static constexpr int MIX_OFF     = SCALES_OFF + C_ * C_;          // 1

// ws layout: per (t,i,j) block record of 8 floats:
//   [0]=inv00 [1]=inv01 [2]=inv11 [3]=logdet [4]=drift_x [5]=drift_y [6]=scale
// ws[2048] = mix
static constexpr int WS_REC = 8;
static constexpr int WS_MIX = T_ * C_ * C_ * WS_REC;  // 2048

__device__ __forceinline__ float sanv(float x) {
    if (isnan(x)) return 0.f;
    return fminf(fmaxf(x, -CLIPV), CLIPV);
}

// ---------------- Kernel 1: per-(t,i,j) block prep (1 block, 256 threads) ---
__global__ __launch_bounds__(256)
void prep_kernel(const float* __restrict__ means,
                 const float* __restrict__ covs,
                 const float* __restrict__ bsr,
                 const float* __restrict__ mixlogit,
                 float* __restrict__ out,
                 float* __restrict__ ws) {
    int tid = threadIdx.x;
    if (tid >= T_ * C_ * C_) return;
    int t = tid >> 4;
    int i = (tid >> 2) & 3;
    int j = tid & 3;
    int bl = tid;  // (t*4+i)*4+j

    // sanitized means
    float mix_ = sanv(means[(t * C_ + i) * 2 + 0]);
    float miy  = sanv(means[(t * C_ + i) * 2 + 1]);
    float mjx  = sanv(means[(t * C_ + j) * 2 + 0]);
    float mjy  = sanv(means[(t * C_ + j) * 2 + 1]);
    float dx = sanv(DT * (mix_ - mjx));
    float dy = sanv(DT * (miy - mjy));
    out[DRIFT_OFF + bl * 2 + 0] = dx;
    out[DRIFT_OFF + bl * 2 + 1] = dy;

    // sanitized+symmetrized covariances
    const float* ci = covs + (t * C_ + i) * 4;
    const float* cj = covs + (t * C_ + j) * 4;
    float ci00 = sanv(ci[0]), ci01 = 0.5f * (sanv(ci[1]) + sanv(ci[2])), ci11 = sanv(ci[3]);
    float cj00 = sanv(cj[0]), cj01 = 0.5f * (sanv(cj[1]) + sanv(cj[2])), cj11 = sanv(cj[3]);

    // disp = I + 2*DT^2*(ci+cj), then san_m(disp + JITTER*I)
    const float k2 = 2.0f * DT * DT;  // 0.005
    float a = sanv(1.0f + k2 * (ci00 + cj00) + JITTER);
    float b = sanv(        k2 * (ci01 + cj01));
    float c = sanv(1.0f + k2 * (ci11 + cj11) + JITTER);

    // _stable_inv_logdet
    float ds = fmaxf(0.5f * (fabsf(a) + fabsf(c)), 1.0f);
    float ra = 0.f, rb = 0.f, rc = 0.f, det0 = 1.f;
    bool found = false;
    float jit = 1e-5f;  // j0 = max(JITTER, 1e-6)
    #pragma unroll
    for (int k = 0; k < 8; ++k) {
        float ja = sanv(a + jit * ds);
        float jb = sanv(b);
        float jc = sanv(c + jit * ds);
        float det = ja * jc - jb * jb;
        if (!found && ja > 0.f && det > 0.f) {
            found = true; ra = ja; rb = jb; rc = jc; det0 = det;
        }
        jit *= 10.f;
    }

    float i00, i01, i11, ld, o00, o01, o11;
    if (found) {
        i00 = sanv(rc / det0);
        i01 = sanv(-rb / det0);
        i11 = sanv(ra / det0);
        ld = logf(det0);
        if (isnan(ld)) ld = 0.f;
        else if (isinf(ld)) ld = (ld > 0.f) ? 20.f : -20.f;
        o00 = ra; o01 = rb; o11 = rc;
    } else {
        float jf = 1e3f;  // j0 * 10^8
        // nan_to_num(diag, nan=1, posinf=CLIP, neginf=1): a,c already finite
        float sd0 = fmaxf(fabsf(a), jf * ds + 1e-4f);
        float sd1 = fmaxf(fabsf(c), jf * ds + 1e-4f);
        o00 = sanv(sd0 + jf * ds); o11 = sanv(sd1 + jf * ds); o01 = 0.f;
        float dg0 = fmaxf(o00, 1e-6f), dg1 = fmaxf(o11, 1e-6f);
        i00 = sanv(1.f / dg0); i11 = sanv(1.f / dg1); i01 = 0.f;
        ld = logf(dg0) + logf(dg1);
        if (isnan(ld)) ld = 0.f;
        else if (isinf(ld)) ld = (ld > 0.f) ? 20.f : -20.f;
    }
    out[DISP_OFF + bl * 4 + 0] = o00;
    out[DISP_OFF + bl * 4 + 1] = o01;
    out[DISP_OFF + bl * 4 + 2] = o01;
    out[DISP_OFF + bl * 4 + 3] = o11;

    // scales: softplus(bsr) + 0.01  (stable: max(x,0)+log1p(exp(-|x|)))
    float x = bsr[i * 4 + j];
    float sc = fmaxf(x, 0.f) + log1pf(expf(-fabsf(x))) + 0.01f;
    if (t == 0) out[SCALES_OFF + i * 4 + j] = sc;

    float* w = ws + bl * WS_REC;
    w[0] = i00; w[1] = i01; w[2] = i11; w[3] = ld;
    w[4] = dx;  w[5] = dy;  w[6] = sc;  w[7] = 0.f;

    if (tid == 0) {
        float lg = mixlogit[0];
        float mx = 1.f / (1.f + expf(-lg));
        out[MIX_OFF] = mx;
        ws[WS_MIX]   = mx;
    }
}

// ---------------- block-wide sum over 256 threads ---------------------------
__device__ __forceinline__ float block_reduce_sum(float v, float* sdata) {
    #pragma unroll
    for (int off = 32; off > 0; off >>= 1) v += __shfl_down(v, off, 64);
    int lane = threadIdx.x & 63, w = threadIdx.x >> 6;
    if (lane == 0) sdata[w] = v;
    __syncthreads();
    float r = sdata[0] + sdata[1] + sdata[2] + sdata[3];
    __syncthreads();  // protect sdata for next reuse
    return r;
}

// ---------------- Kernel 2: one workgroup per output row --------------------
// row r = (t, i, a); thread tid handles columns m*256+tid for m=0..3 (j = m).
__global__ __launch_bounds__(256)
void row_kernel(const float* __restrict__ site,
                const float* __restrict__ ws,
                float* __restrict__ tr) {
    __shared__ float sdata[4];
    int r = blockIdx.x;
    int t = r >> 10;
    int i = (r >> 8) & 3;
    int a = r & 255;
    int tid = threadIdx.x;  // = b

    float ax = site[a * 2 + 0],   ay = site[a * 2 + 1];
    float bx = site[tid * 2 + 0], by = site[tid * 2 + 1];
    float lx = sanv(ax - bx), ly = sanv(ay - by);
    float mx = ws[WS_MIX];

    float v[4];
    #pragma unroll
    for (int m = 0; m < 4; ++m) {
        const float* w = ws + ((t * C_ + i) * C_ + m) * WS_REC;
        float i00 = w[0], i01 = w[1], i11 = w[2], ld = w[3];
        float dx = w[4], dy = w[5], sc = w[6];
        float cx = sanv(lx - dx), cy = sanv(ly - dy);
        float q = i00 * cx * cx + 2.f * i01 * cx * cy + i11 * cy * cy;
        if (isnan(q)) q = 0.f;
        q = fminf(fmaxf(q, 0.f), 60.f);
        float e = fminf(fmaxf(-0.5f * ld - q, -60.f), 20.f);
        float val = sc * expf(e);
        if (isnan(val) || isinf(val)) val = 0.f;
        v[m] = val;
    }

    // normalization #1
    float s1 = block_reduce_sum(v[0] + v[1] + v[2] + v[3], sdata);
    float d1 = fmaxf(s1, JITTER);
    float t1[4];
    #pragma unroll
    for (int m = 0; m < 4; ++m) t1[m] = v[m] / d1;

    // normalization #2
    float s2 = block_reduce_sum(t1[0] + t1[1] + t1[2] + t1[3], sdata);
    float d2 = fmaxf(s2, JITTER);

    // identity mix
    float t3[4];
    #pragma unroll
    for (int m = 0; m < 4; ++m) {
        float t2 = t1[m] / d2;
        float val = (1.f - mx) * t2 + ((m == i && tid == a) ? mx : 0.f);
        if (isnan(val) || isinf(val)) val = 0.f;
        t3[m] = val;
    }

    // normalization #3
    float s3 = block_reduce_sum(t3[0] + t3[1] + t3[2] + t3[3], sdata);
    float d3 = fmaxf(s3, JITTER);

    size_t base = ((size_t)t << 20) + (size_t)(i * S_ + a) * 1024;
    #pragma unroll
    for (int m = 0; m < 4; ++m) {
        tr[base + m * S_ + tid] = t3[m] / d3;
    }
}

extern "C" void kernel_launch(void* const* d_in, const int* in_sizes, int n_in,
                              void* d_out, int out_size, void* d_ws, size_t ws_size,
                              hipStream_t stream) {
    const float* means    = (const float*)d_in[0];
    const float* covs     = (const float*)d_in[1];
    const float* site     = (const float*)d_in[2];
    const float* bsr      = (const float*)d_in[3];
    const float* mixlogit = (const float*)d_in[4];
    float* out = (float*)d_out;
    float* ws  = (float*)d_ws;

    prep_kernel<<<1, 256, 0, stream>>>(means, covs, bsr, mixlogit, out, ws);
    row_kernel<<<T_ * C_ * S_, 256, 0, stream>>>(site, ws, out);
}

// Round 5
// 95.385 us; speedup vs baseline: 1.2037x; 1.2037x over previous
//
#include <hip/hip_runtime.h>
#include <math.h>

// Problem constants (match reference)
#define T_ 16
#define C_ 4
#define S_ 256
static constexpr float DT      = 0.05f;
static constexpr float JITTER  = 1e-5f;
static constexpr float CLIPV   = 1e4f;

// Output layout (floats, concatenated in return order)
static constexpr int TR_SIZE     = T_ * (C_ * S_) * (C_ * S_);   // 16,777,216
static constexpr int DRIFT_OFF   = TR_SIZE;                       // [T,C,C,2] = 512
static constexpr int DISP_OFF    = DRIFT_OFF + T_ * C_ * C_ * 2;  // [T,C,C,2,2] = 1024
static constexpr int SCALES_OFF  = DISP_OFF + T_ * C_ * C_ * 4;   // [C,C] = 16
static constexpr int MIX_OFF     = SCALES_OFF + C_ * C_;          // 1

// ws layout: per (t,i,j) block record of 8 floats:
//   [0]=inv00 [1]=inv01 [2]=inv11 [3]=logdet [4]=drift_x [5]=drift_y [6]=scale
// ws[2048] = mix
static constexpr int WS_REC = 8;
static constexpr int WS_MIX = T_ * C_ * C_ * WS_REC;  // 2048

__device__ __forceinline__ float sanv(float x) {
    if (isnan(x)) return 0.f;
    return fminf(fmaxf(x, -CLIPV), CLIPV);
}

// ---------------- Kernel 1: per-(t,i,j) block prep (1 block, 256 threads) ---
// Unchanged from round 2 (correct, ~2 us, not the bottleneck).
__global__ __launch_bounds__(256)
void prep_kernel(const float* __restrict__ means,
                 const float* __restrict__ covs,
                 const float* __restrict__ bsr,
                 const float* __restrict__ mixlogit,
                 float* __restrict__ out,
                 float* __restrict__ ws) {
    int tid = threadIdx.x;
    if (tid >= T_ * C_ * C_) return;
    int t = tid >> 4;
    int i = (tid >> 2) & 3;
    int j = tid & 3;
    int bl = tid;  // (t*4+i)*4+j

    // sanitized means
    float mix_ = sanv(means[(t * C_ + i) * 2 + 0]);
    float miy  = sanv(means[(t * C_ + i) * 2 + 1]);
    float mjx  = sanv(means[(t * C_ + j) * 2 + 0]);
    float mjy  = sanv(means[(t * C_ + j) * 2 + 1]);
    float dx = sanv(DT * (mix_ - mjx));
    float dy = sanv(DT * (miy - mjy));
    out[DRIFT_OFF + bl * 2 + 0] = dx;
    out[DRIFT_OFF + bl * 2 + 1] = dy;

    // sanitized+symmetrized covariances
    const float* ci = covs + (t * C_ + i) * 4;
    const float* cj = covs + (t * C_ + j) * 4;
    float ci00 = sanv(ci[0]), ci01 = 0.5f * (sanv(ci[1]) + sanv(ci[2])), ci11 = sanv(ci[3]);
    float cj00 = sanv(cj[0]), cj01 = 0.5f * (sanv(cj[1]) + sanv(cj[2])), cj11 = sanv(cj[3]);

    // disp = I + 2*DT^2*(ci+cj), then san_m(disp + JITTER*I)
    const float k2 = 2.0f * DT * DT;  // 0.005
    float a = sanv(1.0f + k2 * (ci00 + cj00) + JITTER);
    float b = sanv(        k2 * (ci01 + cj01));
    float c = sanv(1.0f + k2 * (ci11 + cj11) + JITTER);

    // _stable_inv_logdet
    float ds = fmaxf(0.5f * (fabsf(a) + fabsf(c)), 1.0f);
    float ra = 0.f, rb = 0.f, rc = 0.f, det0 = 1.f;
    bool found = false;
    float jit = 1e-5f;  // j0 = max(JITTER, 1e-6)
    #pragma unroll
    for (int k = 0; k < 8; ++k) {
        float ja = sanv(a + jit * ds);
        float jb = sanv(b);
        float jc = sanv(c + jit * ds);
        float det = ja * jc - jb * jb;
        if (!found && ja > 0.f && det > 0.f) {
            found = true; ra = ja; rb = jb; rc = jc; det0 = det;
        }
        jit *= 10.f;
    }

    float i00, i01, i11, ld, o00, o01, o11;
    if (found) {
        i00 = sanv(rc / det0);
        i01 = sanv(-rb / det0);
        i11 = sanv(ra / det0);
        ld = logf(det0);
        if (isnan(ld)) ld = 0.f;
        else if (isinf(ld)) ld = (ld > 0.f) ? 20.f : -20.f;
        o00 = ra; o01 = rb; o11 = rc;
    } else {
        float jf = 1e3f;  // j0 * 10^8
        float sd0 = fmaxf(fabsf(a), jf * ds + 1e-4f);
        float sd1 = fmaxf(fabsf(c), jf * ds + 1e-4f);
        o00 = sanv(sd0 + jf * ds); o11 = sanv(sd1 + jf * ds); o01 = 0.f;
        float dg0 = fmaxf(o00, 1e-6f), dg1 = fmaxf(o11, 1e-6f);
        i00 = sanv(1.f / dg0); i11 = sanv(1.f / dg1); i01 = 0.f;
        ld = logf(dg0) + logf(dg1);
        if (isnan(ld)) ld = 0.f;
        else if (isinf(ld)) ld = (ld > 0.f) ? 20.f : -20.f;
    }
    out[DISP_OFF + bl * 4 + 0] = o00;
    out[DISP_OFF + bl * 4 + 1] = o01;
    out[DISP_OFF + bl * 4 + 2] = o01;
    out[DISP_OFF + bl * 4 + 3] = o11;

    // scales: softplus(bsr) + 0.01  (stable: max(x,0)+log1p(exp(-|x|)))
    float x = bsr[i * 4 + j];
    float sc = fmaxf(x, 0.f) + log1pf(expf(-fabsf(x))) + 0.01f;
    if (t == 0) out[SCALES_OFF + i * 4 + j] = sc;

    float* w = ws + bl * WS_REC;
    w[0] = i00; w[1] = i01; w[2] = i11; w[3] = ld;
    w[4] = dx;  w[5] = dy;  w[6] = sc;  w[7] = 0.f;

    if (tid == 0) {
        float lg = mixlogit[0];
        float mx = 1.f / (1.f + expf(-lg));
        out[MIX_OFF] = mx;
        ws[WS_MIX]   = mx;
    }
}

// ---------------- block-wide sum over 256 threads (ONE barrier pair) --------
__device__ __forceinline__ float block_reduce_sum(float v, float* sdata) {
    #pragma unroll
    for (int off = 32; off > 0; off >>= 1) v += __shfl_down(v, off, 64);
    int lane = threadIdx.x & 63, w = threadIdx.x >> 6;
    if (lane == 0) sdata[w] = v;
    __syncthreads();
    return sdata[0] + sdata[1] + sdata[2] + sdata[3];
}

// ---------------- Kernel 2: one workgroup per output row --------------------
// row r = (t, i, a); thread tid handles columns m*256+tid for m=0..3 (j = m).
// Algebraic collapse: with s1 = sum(v), d1 = max(s1,eps),
//   row-sum after div #1 is exactly s1/d1  -> s2, d2
//   row-sum after mix is (1-mx)*(s2/d2)+mx -> s3, d3
// so final out = v * (1-mx)/(d1*d2*d3) + delta_diag * mx/d3. ONE reduction.
__global__ __launch_bounds__(256)
void row_kernel(const float* __restrict__ site,
                const float* __restrict__ ws,
                float* __restrict__ tr) {
    __shared__ float sdata[4];
    int r = blockIdx.x;
    int t = r >> 10;
    int i = (r >> 8) & 3;
    int a = r & 255;
    int tid = threadIdx.x;  // = b

    float2 sb = ((const float2*)site)[tid];
    float2 sa = ((const float2*)site)[a];       // block-uniform
    float lx = sa.x - sb.x, ly = sa.y - sb.y;   // site coords finite & < CLIP: san is identity
    float mx = ws[WS_MIX];

    float v[4];
    #pragma unroll
    for (int m = 0; m < 4; ++m) {
        const float* w = ws + ((t * C_ + i) * C_ + m) * WS_REC;  // block-uniform -> scalar loads
        float i00 = w[0], i01 = w[1], i11 = w[2], ld = w[3];
        float dx = w[4], dy = w[5], sc = w[6];
        float cx = lx - dx, cy = ly - dy;
        float q = i00 * cx * cx + 2.f * i01 * cx * cy + i11 * cy * cy;
        q = fminf(fmaxf(q, 0.f), 60.f);                           // binding clip: keep
        float e = fminf(fmaxf(-0.5f * ld - q, -60.f), 20.f);      // binding clip: keep
        v[m] = sc * __expf(e);                                    // v_exp_f32
    }

    float s1 = block_reduce_sum(v[0] + v[1] + v[2] + v[3], sdata);
    float d1 = fmaxf(s1, JITTER);
    float s2 = s1 / d1;
    float d2 = fmaxf(s2, JITTER);
    float sum_t2 = s2 / d2;
    float s3 = (1.f - mx) * sum_t2 + mx;
    float d3 = fmaxf(s3, JITTER);
    float scale = (1.f - mx) / (d1 * d2 * d3);
    float diag  = mx / d3;

    size_t base = ((size_t)t << 20) + (size_t)(i * S_ + a) * 1024;
    #pragma unroll
    for (int m = 0; m < 4; ++m) {
        float o = v[m] * scale;
        if (m == i && tid == a) o += diag;   // diagonal of the (i,i) block
        tr[base + m * S_ + tid] = o;
    }
}

extern "C" void kernel_launch(void* const* d_in, const int* in_sizes, int n_in,
                              void* d_out, int out_size, void* d_ws, size_t ws_size,
                              hipStream_t stream) {
    const float* means    = (const float*)d_in[0];
    const float* covs     = (const float*)d_in[1];
    const float* site     = (const float*)d_in[2];
    const float* bsr      = (const float*)d_in[3];
    const float* mixlogit = (const float*)d_in[4];
    float* out = (float*)d_out;
    float* ws  = (float*)d_ws;

    prep_kernel<<<1, 256, 0, stream>>>(means, covs, bsr, mixlogit, out, ws);
    row_kernel<<<T_ * C_ * S_, 256, 0, stream>>>(site, ws, out);
}

// Round 12
// 93.832 us; speedup vs baseline: 1.2236x; 1.0166x over previous
//
#include <hip/hip_runtime.h>
#include <math.h>

// Problem constants (match reference)
#define T_ 16
#define C_ 4
#define S_ 256
static constexpr float DT      = 0.05f;
static constexpr float JITTER  = 1e-5f;
static constexpr float CLIPV   = 1e4f;

typedef float f32x4 __attribute__((ext_vector_type(4)));

// Output layout (floats, concatenated in return order)
static constexpr int TR_SIZE     = T_ * (C_ * S_) * (C_ * S_);   // 16,777,216
static constexpr int DRIFT_OFF   = TR_SIZE;                       // [T,C,C,2] = 512
static constexpr int DISP_OFF    = DRIFT_OFF + T_ * C_ * C_ * 2;  // [T,C,C,2,2] = 1024
static constexpr int SCALES_OFF  = DISP_OFF + T_ * C_ * C_ * 4;   // [C,C] = 16
static constexpr int MIX_OFF     = SCALES_OFF + C_ * C_;          // 1

// ws layout: per (t,i,j) block record of 8 floats:
//   [0]=inv00 [1]=inv01 [2]=inv11 [3]=h(=-0.5*logdet) [4]=drift_x [5]=drift_y [6]=scale
// ws[2048] = mix
static constexpr int WS_REC = 8;
static constexpr int WS_MIX = T_ * C_ * C_ * WS_REC;  // 2048

__device__ __forceinline__ float sanv(float x) {
    if (isnan(x)) return 0.f;
    return fminf(fmaxf(x, -CLIPV), CLIPV);
}

// ---------------- Kernel 1: per-(t,i,j) block prep (1 block, 256 threads) ---
__global__ __launch_bounds__(256)
void prep_kernel(const float* __restrict__ means,
                 const float* __restrict__ covs,
                 const float* __restrict__ bsr,
                 const float* __restrict__ mixlogit,
                 float* __restrict__ out,
                 float* __restrict__ ws) {
    int tid = threadIdx.x;
    if (tid >= T_ * C_ * C_) return;
    int t = tid >> 4;
    int i = (tid >> 2) & 3;
    int j = tid & 3;
    int bl = tid;  // (t*4+i)*4+j

    // sanitized means
    float mix_ = sanv(means[(t * C_ + i) * 2 + 0]);
    float miy  = sanv(means[(t * C_ + i) * 2 + 1]);
    float mjx  = sanv(means[(t * C_ + j) * 2 + 0]);
    float mjy  = sanv(means[(t * C_ + j) * 2 + 1]);
    float dx = sanv(DT * (mix_ - mjx));
    float dy = sanv(DT * (miy - mjy));
    out[DRIFT_OFF + bl * 2 + 0] = dx;
    out[DRIFT_OFF + bl * 2 + 1] = dy;

    // sanitized+symmetrized covariances
    const float* ci = covs + (t * C_ + i) * 4;
    const float* cj = covs + (t * C_ + j) * 4;
    float ci00 = sanv(ci[0]), ci01 = 0.5f * (sanv(ci[1]) + sanv(ci[2])), ci11 = sanv(ci[3]);
    float cj00 = sanv(cj[0]), cj01 = 0.5f * (sanv(cj[1]) + sanv(cj[2])), cj11 = sanv(cj[3]);

    // disp = I + 2*DT^2*(ci+cj), then san_m(disp + JITTER*I)
    const float k2 = 2.0f * DT * DT;  // 0.005
    float a = sanv(1.0f + k2 * (ci00 + cj00) + JITTER);
    float b = sanv(        k2 * (ci01 + cj01));
    float c = sanv(1.0f + k2 * (ci11 + cj11) + JITTER);

    // _stable_inv_logdet
    float ds = fmaxf(0.5f * (fabsf(a) + fabsf(c)), 1.0f);
    float ra = 0.f, rb = 0.f, rc = 0.f, det0 = 1.f;
    bool found = false;
    float jit = 1e-5f;  // j0 = max(JITTER, 1e-6)
    #pragma unroll
    for (int k = 0; k < 8; ++k) {
        float ja = sanv(a + jit * ds);
        float jb = sanv(b);
        float jc = sanv(c + jit * ds);
        float det = ja * jc - jb * jb;
        if (!found && ja > 0.f && det > 0.f) {
            found = true; ra = ja; rb = jb; rc = jc; det0 = det;
        }
        jit *= 10.f;
    }

    float i00, i01, i11, ld, o00, o01, o11;
    if (found) {
        i00 = sanv(rc / det0);
        i01 = sanv(-rb / det0);
        i11 = sanv(ra / det0);
        ld = logf(det0);
        if (isnan(ld)) ld = 0.f;
        else if (isinf(ld)) ld = (ld > 0.f) ? 20.f : -20.f;
        o00 = ra; o01 = rb; o11 = rc;
    } else {
        float jf = 1e3f;  // j0 * 10^8
        float sd0 = fmaxf(fabsf(a), jf * ds + 1e-4f);
        float sd1 = fmaxf(fabsf(c), jf * ds + 1e-4f);
        o00 = sanv(sd0 + jf * ds); o11 = sanv(sd1 + jf * ds); o01 = 0.f;
        float dg0 = fmaxf(o00, 1e-6f), dg1 = fmaxf(o11, 1e-6f);
        i00 = sanv(1.f / dg0); i11 = sanv(1.f / dg1); i01 = 0.f;
        ld = logf(dg0) + logf(dg1);
        if (isnan(ld)) ld = 0.f;
        else if (isinf(ld)) ld = (ld > 0.f) ? 20.f : -20.f;
    }
    out[DISP_OFF + bl * 4 + 0] = o00;
    out[DISP_OFF + bl * 4 + 1] = o01;
    out[DISP_OFF + bl * 4 + 2] = o01;
    out[DISP_OFF + bl * 4 + 3] = o11;

    // scales: softplus(bsr) + 0.01  (stable: max(x,0)+log1p(exp(-|x|)))
    float x = bsr[i * 4 + j];
    float sc = fmaxf(x, 0.f) + log1pf(expf(-fabsf(x))) + 0.01f;
    if (t == 0) out[SCALES_OFF + i * 4 + j] = sc;

    float* w = ws + bl * WS_REC;
    w[0] = i00; w[1] = i01; w[2] = i11; w[3] = -0.5f * ld;  // h = -0.5*logdet
    w[4] = dx;  w[5] = dy;  w[6] = sc;  w[7] = 0.f;

    if (tid == 0) {
        float lg = mixlogit[0];
        float mx = 1.f / (1.f + expf(-lg));
        out[MIX_OFF] = mx;
        ws[WS_MIX]   = mx;
    }
}

// ---------------- Kernel 2: one workgroup per output row --------------------
// row r = (t, i, a). Thread tid covers the 4 CONSECUTIVE global columns
// 4*tid..4*tid+3 of the 1024-wide row -> one 16B store per thread.
// j-block = tid>>6 == wave id (wave-uniform ws record via readfirstlane);
// within-block site index b = 4*(tid&63)+k  <-- lane-local, NOT 4*tid (r9 bug).
// Algebraic collapse of the 3 normalizations (see r2): one block reduction;
//   final out = v * (1-mx)/(d1*d2*d3) + delta_diag * mx/d3.
__global__ __launch_bounds__(256)
void row_kernel(const float* __restrict__ site,
                const float* __restrict__ ws,
                float* __restrict__ tr) {
    __shared__ float sdata[4];
    int r = blockIdx.x;
    int t = r >> 10;
    int i = (r >> 8) & 3;
    int a = r & 255;
    int tid = threadIdx.x;
    int lane = tid & 63;                                  // lane within wave
    int wid = __builtin_amdgcn_readfirstlane(tid >> 6);   // wave-uniform j-block

    // 4 consecutive sites within the j-block: b = 4*lane..4*lane+3
    // (site array is 256 float2 = 128 f32x4; max index 2*63+1 = 127: in bounds)
    const f32x4* s4 = (const f32x4*)site;
    f32x4 p0 = s4[2 * lane];
    f32x4 p1 = s4[2 * lane + 1];
    float2 sa = ((const float2*)site)[a];        // block-uniform
    float mx = ws[WS_MIX];

    const float* w = ws + ((t * C_ + i) * C_ + wid) * WS_REC;  // wave-uniform
    float i00 = w[0], i01 = w[1], i11 = w[2], h = w[3];
    float dx = w[4],  dy = w[5],  sc = w[6];
    float ox = sa.x - dx, oy = sa.y - dy;        // centered = (sa - drift) - sb

    float bx[4] = {p0.x, p0.z, p1.x, p1.z};
    float by[4] = {p0.y, p0.w, p1.y, p1.w};

    float v[4];
    #pragma unroll
    for (int k = 0; k < 4; ++k) {
        float cx = ox - bx[k], cy = oy - by[k];
        float u = i00 * cx + i01 * cy;
        float z = i01 * cx + i11 * cy;
        float q = cx * u + cy * z;
        q = fminf(fmaxf(q, 0.f), 60.f);                      // binding clip: keep
        float e = fminf(fmaxf(h - q, -60.f), 20.f);          // binding clip: keep
        v[k] = sc * __expf(e);
    }

    // one block reduction: wave shfl-reduce, then 4 partials via LDS
    float local = (v[0] + v[1]) + (v[2] + v[3]);
    #pragma unroll
    for (int off = 32; off > 0; off >>= 1) local += __shfl_down(local, off, 64);
    if (lane == 0) sdata[wid] = local;
    __syncthreads();
    float s1 = sdata[0] + sdata[1] + sdata[2] + sdata[3];

    // uniform epilogue with v_rcp_f32 (rel err ~1e-7 << absmax headroom)
    float d1 = fmaxf(s1, JITTER);
    float r1 = __builtin_amdgcn_rcpf(d1);
    float s2 = s1 * r1;
    float d2 = fmaxf(s2, JITTER);
    float r2 = __builtin_amdgcn_rcpf(d2);
    float sum_t2 = s2 * r2;
    float omx = 1.f - mx;
    float s3 = omx * sum_t2 + mx;
    float d3 = fmaxf(s3, JITTER);
    float r3 = __builtin_amdgcn_rcpf(d3);
    float scale = omx * r1 * r2 * r3;
    float diag  = mx * r3;

    f32x4 o;
    o.x = v[0] * scale; o.y = v[1] * scale;
    o.z = v[2] * scale; o.w = v[3] * scale;
    // diagonal of the (i,i) block: j==i and b==a -> wave i, lane a>>2, slot a&3
    if (wid == i && lane == (a >> 2)) {
        int sl = a & 3;
        if      (sl == 0) o.x += diag;
        else if (sl == 1) o.y += diag;
        else if (sl == 2) o.z += diag;
        else              o.w += diag;
    }

    size_t base = ((size_t)t << 20) + (size_t)(i * S_ + a) * 1024;
    __builtin_nontemporal_store(o, (f32x4*)(tr + base) + tid);
}

extern "C" void kernel_launch(void* const* d_in, const int* in_sizes, int n_in,
                              void* d_out, int out_size, void* d_ws, size_t ws_size,
                              hipStream_t stream) {
    const float* means    = (const float*)d_in[0];
    const float* covs     = (const float*)d_in[1];
    const float* site     = (const float*)d_in[2];
    const float* bsr      = (const float*)d_in[3];
    const float* mixlogit = (const float*)d_in[4];
    float* out = (float*)d_out;
    float* ws  = (float*)d_ws;

    prep_kernel<<<1, 256, 0, stream>>>(means, covs, bsr, mixlogit, out, ws);
    row_kernel<<<T_ * C_ * S_, 256, 0, stream>>>(site, ws, out);
}

// Round 13
// 90.191 us; speedup vs baseline: 1.2730x; 1.0404x over previous
//
#include <hip/hip_runtime.h>
#include <math.h>

// Problem constants (match reference)
#define T_ 16
#define C_ 4
#define S_ 256
static constexpr float DT      = 0.05f;
static constexpr float JITTER  = 1e-5f;
static constexpr float CLIPV   = 1e4f;

typedef float f32x4 __attribute__((ext_vector_type(4)));

// Output layout (floats, concatenated in return order)
static constexpr int TR_SIZE     = T_ * (C_ * S_) * (C_ * S_);   // 16,777,216
static constexpr int DRIFT_OFF   = TR_SIZE;                       // [T,C,C,2] = 512
static constexpr int DISP_OFF    = DRIFT_OFF + T_ * C_ * C_ * 2;  // [T,C,C,2,2] = 1024
static constexpr int SCALES_OFF  = DISP_OFF + T_ * C_ * C_ * 4;   // [C,C] = 16
static constexpr int MIX_OFF     = SCALES_OFF + C_ * C_;          // 1

// ws layout: per (t,i,j) block record of 8 floats:
//   [0]=inv00 [1]=inv01 [2]=inv11 [3]=h(=-0.5*logdet) [4]=drift_x [5]=drift_y [6]=scale
// ws[2048] = mix
static constexpr int WS_REC = 8;
static constexpr int WS_MIX = T_ * C_ * C_ * WS_REC;  // 2048

__device__ __forceinline__ float sanv(float x) {
    if (isnan(x)) return 0.f;
    return fminf(fmaxf(x, -CLIPV), CLIPV);
}

// ---------------- Kernel 1: per-(t,i,j) block prep (1 block, 256 threads) ---
__global__ __launch_bounds__(256)
void prep_kernel(const float* __restrict__ means,
                 const float* __restrict__ covs,
                 const float* __restrict__ bsr,
                 const float* __restrict__ mixlogit,
                 float* __restrict__ out,
                 float* __restrict__ ws) {
    int tid = threadIdx.x;
    if (tid >= T_ * C_ * C_) return;
    int t = tid >> 4;
    int i = (tid >> 2) & 3;
    int j = tid & 3;
    int bl = tid;  // (t*4+i)*4+j

    // sanitized means
    float mix_ = sanv(means[(t * C_ + i) * 2 + 0]);
    float miy  = sanv(means[(t * C_ + i) * 2 + 1]);
    float mjx  = sanv(means[(t * C_ + j) * 2 + 0]);
    float mjy  = sanv(means[(t * C_ + j) * 2 + 1]);
    float dx = sanv(DT * (mix_ - mjx));
    float dy = sanv(DT * (miy - mjy));
    out[DRIFT_OFF + bl * 2 + 0] = dx;
    out[DRIFT_OFF + bl * 2 + 1] = dy;

    // sanitized+symmetrized covariances
    const float* ci = covs + (t * C_ + i) * 4;
    const float* cj = covs + (t * C_ + j) * 4;
    float ci00 = sanv(ci[0]), ci01 = 0.5f * (sanv(ci[1]) + sanv(ci[2])), ci11 = sanv(ci[3]);
    float cj00 = sanv(cj[0]), cj01 = 0.5f * (sanv(cj[1]) + sanv(cj[2])), cj11 = sanv(cj[3]);

    // disp = I + 2*DT^2*(ci+cj), then san_m(disp + JITTER*I)
    const float k2 = 2.0f * DT * DT;  // 0.005
    float a = sanv(1.0f + k2 * (ci00 + cj00) + JITTER);
    float b = sanv(        k2 * (ci01 + cj01));
    float c = sanv(1.0f + k2 * (ci11 + cj11) + JITTER);

    // _stable_inv_logdet
    float ds = fmaxf(0.5f * (fabsf(a) + fabsf(c)), 1.0f);
    float ra = 0.f, rb = 0.f, rc = 0.f, det0 = 1.f;
    bool found = false;
    float jit = 1e-5f;  // j0 = max(JITTER, 1e-6)
    #pragma unroll
    for (int k = 0; k < 8; ++k) {
        float ja = sanv(a + jit * ds);
        float jb = sanv(b);
        float jc = sanv(c + jit * ds);
        float det = ja * jc - jb * jb;
        if (!found && ja > 0.f && det > 0.f) {
            found = true; ra = ja; rb = jb; rc = jc; det0 = det;
        }
        jit *= 10.f;
    }

    float i00, i01, i11, ld, o00, o01, o11;
    if (found) {
        i00 = sanv(rc / det0);
        i01 = sanv(-rb / det0);
        i11 = sanv(ra / det0);
        ld = logf(det0);
        if (isnan(ld)) ld = 0.f;
        else if (isinf(ld)) ld = (ld > 0.f) ? 20.f : -20.f;
        o00 = ra; o01 = rb; o11 = rc;
    } else {
        float jf = 1e3f;  // j0 * 10^8
        float sd0 = fmaxf(fabsf(a), jf * ds + 1e-4f);
        float sd1 = fmaxf(fabsf(c), jf * ds + 1e-4f);
        o00 = sanv(sd0 + jf * ds); o11 = sanv(sd1 + jf * ds); o01 = 0.f;
        float dg0 = fmaxf(o00, 1e-6f), dg1 = fmaxf(o11, 1e-6f);
        i00 = sanv(1.f / dg0); i11 = sanv(1.f / dg1); i01 = 0.f;
        ld = logf(dg0) + logf(dg1);
        if (isnan(ld)) ld = 0.f;
        else if (isinf(ld)) ld = (ld > 0.f) ? 20.f : -20.f;
    }
    out[DISP_OFF + bl * 4 + 0] = o00;
    out[DISP_OFF + bl * 4 + 1] = o01;
    out[DISP_OFF + bl * 4 + 2] = o01;
    out[DISP_OFF + bl * 4 + 3] = o11;

    // scales: softplus(bsr) + 0.01  (stable: max(x,0)+log1p(exp(-|x|)))
    float x = bsr[i * 4 + j];
    float sc = fmaxf(x, 0.f) + log1pf(expf(-fabsf(x))) + 0.01f;
    if (t == 0) out[SCALES_OFF + i * 4 + j] = sc;

    float* w = ws + bl * WS_REC;
    w[0] = i00; w[1] = i01; w[2] = i11; w[3] = -0.5f * ld;  // h = -0.5*logdet
    w[4] = dx;  w[5] = dy;  w[6] = sc;  w[7] = 0.f;

    if (tid == 0) {
        float lg = mixlogit[0];
        float mx = 1.f / (1.f + expf(-lg));
        out[MIX_OFF] = mx;
        ws[WS_MIX]   = mx;
    }
}

// ---------------- Kernel 2: ONE WAVE PER ROW (no LDS, no barrier) ----------
// Row r = blockIdx.x*4 + wave = (t, i, a). Each lane covers 16 columns:
// for store k (=j-block, 0..3), lane l writes columns k*256 + 4l .. 4l+3
// -> 1 KB contiguous per store instruction, ws record wave-uniform per k,
// site pairs loaded once per lane and reused across all 4 k.
// Row sum via 6-step __shfl_xor butterfly (all lanes get s1). Epilogue is
// the r2 algebraic collapse: out = v*(1-mx)/(d1*d2*d3) + delta_diag*mx/d3.
__global__ __launch_bounds__(256)
void row_kernel(const float* __restrict__ site,
                const float* __restrict__ ws,
                float* __restrict__ tr) {
    int tid  = threadIdx.x;
    int lane = tid & 63;
    int r = __builtin_amdgcn_readfirstlane((blockIdx.x << 2) | (tid >> 6));
    int t = r >> 10;
    int i = (r >> 8) & 3;
    int a = r & 255;

    // lane's 4 sites: b = 4*lane .. 4*lane+3 (128 f32x4 total; max idx 127)
    const f32x4* s4 = (const f32x4*)site;
    f32x4 p0 = s4[2 * lane];
    f32x4 p1 = s4[2 * lane + 1];
    float2 sa = ((const float2*)site)[a];        // wave-uniform
    float mx = ws[WS_MIX];

    float bx[4] = {p0.x, p0.z, p1.x, p1.z};
    float by[4] = {p0.y, p0.w, p1.y, p1.w};

    float v[4][4];
    float local = 0.f;
    #pragma unroll
    for (int k = 0; k < 4; ++k) {                // k = j-block, wave-uniform record
        const float* w = ws + ((t * C_ + i) * C_ + k) * WS_REC;
        float i00 = w[0], i01 = w[1], i11 = w[2], h = w[3];
        float dx = w[4],  dy = w[5],  sc = w[6];
        float ox = sa.x - dx, oy = sa.y - dy;
        #pragma unroll
        for (int s = 0; s < 4; ++s) {
            float cx = ox - bx[s], cy = oy - by[s];
            float u = i00 * cx + i01 * cy;
            float z = i01 * cx + i11 * cy;
            float q = cx * u + cy * z;
            q = fminf(fmaxf(q, 0.f), 60.f);                 // binding clip: keep
            float e = fminf(fmaxf(h - q, -60.f), 20.f);     // binding clip: keep
            float val = sc * __expf(e);
            v[k][s] = val;
            local += val;
        }
    }

    // 64-lane butterfly all-reduce (no LDS, no barrier)
    #pragma unroll
    for (int m = 1; m < 64; m <<= 1) local += __shfl_xor(local, m, 64);
    float s1 = local;

    // uniform epilogue with v_rcp_f32 (rel err ~1e-7 << absmax headroom)
    float d1 = fmaxf(s1, JITTER);
    float r1 = __builtin_amdgcn_rcpf(d1);
    float s2 = s1 * r1;
    float d2 = fmaxf(s2, JITTER);
    float r2 = __builtin_amdgcn_rcpf(d2);
    float sum_t2 = s2 * r2;
    float omx = 1.f - mx;
    float s3 = omx * sum_t2 + mx;
    float d3 = fmaxf(s3, JITTER);
    float r3 = __builtin_amdgcn_rcpf(d3);
    float scale = omx * r1 * r2 * r3;
    float diag  = mx * r3;

    size_t base = ((size_t)t << 20) + (size_t)(i * S_ + a) * 1024;
    f32x4* dst = (f32x4*)(tr + base);
    #pragma unroll
    for (int k = 0; k < 4; ++k) {
        f32x4 o;
        o.x = v[k][0] * scale; o.y = v[k][1] * scale;
        o.z = v[k][2] * scale; o.w = v[k][3] * scale;
        // diagonal of the (i,i) block: k==i, lane a>>2, slot a&3
        if (k == i && lane == (a >> 2)) {
            int sl = a & 3;
            if      (sl == 0) o.x += diag;
            else if (sl == 1) o.y += diag;
            else if (sl == 2) o.z += diag;
            else              o.w += diag;
        }
        __builtin_nontemporal_store(o, dst + (k << 6) + lane);
    }
}

extern "C" void kernel_launch(void* const* d_in, const int* in_sizes, int n_in,
                              void* d_out, int out_size, void* d_ws, size_t ws_size,
                              hipStream_t stream) {
    const float* means    = (const float*)d_in[0];
    const float* covs     = (const float*)d_in[1];
    const float* site     = (const float*)d_in[2];
    const float* bsr      = (const float*)d_in[3];
    const float* mixlogit = (const float*)d_in[4];
    float* out = (float*)d_out;
    float* ws  = (float*)d_ws;

    prep_kernel<<<1, 256, 0, stream>>>(means, covs, bsr, mixlogit, out, ws);
    row_kernel<<<(T_ * C_ * S_) / 4, 256, 0, stream>>>(site, ws, out);
}